// Round 13
// baseline (175.874 us; speedup 1.0000x reference)
//
#include <hip/hip_runtime.h>
#include <hip/hip_bf16.h>

// Problem constants
#define B_   8
#define D1_  1024
#define DJ_  512
#define S_   2048
#define OUT_ 2048
#define IN_  2048          // D1 + 2*DJ
#define M_TOT (B_ * S_)    // 16384

typedef __attribute__((ext_vector_type(8)))  short          bf16x8;
typedef __attribute__((ext_vector_type(8)))  unsigned short ushort8;
typedef __attribute__((ext_vector_type(16))) float          f32x16;

typedef __attribute__((address_space(3))) unsigned int as3_uint;
typedef __attribute__((address_space(1))) unsigned int as1_uint;

__device__ __forceinline__ unsigned short f2bf(float f) {
    union { float f; unsigned u; } v; v.f = f;
    unsigned r = v.u + 0x7FFF + ((v.u >> 16) & 1);   // round-to-nearest-even
    return (unsigned short)(r >> 16);
}

__device__ __forceinline__ void gload_lds16(const void* g, const void* l) {
    __builtin_amdgcn_global_load_lds(
        (const as1_uint*)(unsigned long long)g,
        (as3_uint*)(unsigned int)(unsigned long long)l,
        16, 0, 0);
}

// ---------------------------------------------------------------------------
// Kernel 1 (merged prep, == round 7/12): blocks [0,8192) = concat+transpose+cvt;
// blocks [8192,10240) = W f32->bf16.  Runs at ~memory roofline (~33us).
__global__ __launch_bounds__(256) void prep_kernel(
        const float* __restrict__ in1, const float* __restrict__ in2a,
        const float* __restrict__ in2b, const float* __restrict__ W,
        unsigned short* __restrict__ Xt, unsigned short* __restrict__ Wb) {
    int bid = blockIdx.x;
    if (bid >= 8192) {
        size_t i = (size_t)(bid - 8192) * 256 + threadIdx.x;
        const float4* p = reinterpret_cast<const float4*>(W) + i * 2;
        float4 a = p[0], c = p[1];
        ushort8 h;
        h[0] = f2bf(a.x); h[1] = f2bf(a.y); h[2] = f2bf(a.z); h[3] = f2bf(a.w);
        h[4] = f2bf(c.x); h[5] = f2bf(c.y); h[6] = f2bf(c.z); h[7] = f2bf(c.w);
        *(reinterpret_cast<ushort8*>(Wb) + i) = h;
        return;
    }
    __shared__ float tile[64][65];
    int st = bid & 31;
    int ft = (bid >> 5) & 31;
    int b  = bid >> 10;
    int f0 = ft << 6, s0 = st << 6;

    const float* src; int frel;
    if (f0 < D1_)             { src = in1  + (size_t)b * D1_ * S_; frel = f0; }
    else if (f0 < D1_ + DJ_)  { src = in2a + (size_t)b * DJ_ * S_; frel = f0 - D1_; }
    else                      { src = in2b + (size_t)b * DJ_ * S_; frel = f0 - (D1_ + DJ_); }

    int t = threadIdx.x;
    int tr = t >> 4, tc = t & 15;
    #pragma unroll
    for (int i = 0; i < 4; ++i) {
        int fi = tr + i * 16;
        const float4 v = *reinterpret_cast<const float4*>(
            &src[(size_t)(frel + fi) * S_ + s0 + tc * 4]);
        tile[fi][tc * 4 + 0] = v.x; tile[fi][tc * 4 + 1] = v.y;
        tile[fi][tc * 4 + 2] = v.z; tile[fi][tc * 4 + 3] = v.w;
    }
    __syncthreads();
    int si0 = t >> 3, fx = t & 7;
    #pragma unroll
    for (int i = 0; i < 2; ++i) {
        int si = si0 + i * 32;
        ushort8 h;
        #pragma unroll
        for (int j = 0; j < 8; ++j) h[j] = f2bf(tile[fx * 8 + j][si]);
        *reinterpret_cast<ushort8*>(
            &Xt[(size_t)(b * S_ + s0 + si) * IN_ + f0 + fx * 8]) = h;
    }
}

// ---------------------------------------------------------------------------
// Kernel 2: 256x256 bf16 GEMM (round 13) = round-12 skeleton (proven 123us:
// stages, fences, barriers, prologue byte-identical) with the MFMA shape
// switched 16x16x32 -> 32x32x16 (µbench 2075 -> 2382+ TF, half the MFMA
// instruction count).
// C[M,N] = A[M,K]*B[N,K]^T + bias.  512 thr = 8 waves (2M x 4N).
// LDS: As_/Bs_ [2 buf][2 region][128][64] bf16 = 128 KiB.  T2 swizzle both.
// Per-wave output 128x64 = 4 row-tiles x 2 col-tiles of 32x32.
// Fragment layouts (32x32x16):
//   A in: row = lane&31, k = (lane>>5)*8 + j   (8 bf16 / lane, b128 read)
//   B in: col = lane&31, k = (lane>>5)*8 + j
//   C/D:  col = lane&31, row = (reg&3) + 8*(reg>>2) + 4*(lane>>5)  [m74/m101]
// LDS reads: READ_A2 = 8 b128 / quadrant (2 row-tiles x 4 k-subtiles);
// READ_B32 = 4 b128 / col-tile; bytes/K-tile unchanged (each element once).
// Bank math: within a quarter-wave, 8 phys slots x 2 lanes/bank -> free (m136).

__global__ __launch_bounds__(512, 2) void gemm256_kernel(
        const unsigned short* __restrict__ A,    // Xt [M_TOT][IN_] bf16
        const unsigned short* __restrict__ Bm,   // Wb [OUT_][IN_] bf16
        const float* __restrict__ bias,
        float* __restrict__ C) {
    __shared__ unsigned short As_[32768];   // [2][2][128][64]
    __shared__ unsigned short Bs_[32768];

    int bid = blockIdx.x;
    // XCD swizzle: nwg = 512 = 8 * 64 (divisible -> simple form bijective)
    int swz = (bid & 7) * 64 + (bid >> 3);
    int m0 = (swz >> 3) * 256;
    int n0 = (swz & 7) * 256;

    int t = threadIdx.x;
    int lane = t & 63, wave = t >> 6;
    int wm = wave >> 2;
    int wn = wave & 3;
    int lane31 = lane & 31;
    int khi    = lane >> 5;        // k-half selector

    // staging constants
    int sr  = t >> 3;
    int sc  = t & 7;
    int swc = sc ^ (sr & 7);       // pre-swizzled global k-slot (involution)

    // fragment addressing
    int alr0 = wm * 64 + lane31;   // A region-local row, row-tile ii adds ii*32
    int asw  = alr0 & 7;           // (lr&7) invariant under +32
    int blr  = wn * 32 + lane31;   // B region-local row
    int bsw  = blr & 7;

#define STAGE_A(bb, h, kt) do { \
    const unsigned short* _g0 = A + (size_t)(m0 + (h)*64 + sr) * IN_ + (kt) + swc*8; \
    const unsigned short* _g1 = A + (size_t)(m0 + 128 + (h)*64 + sr) * IN_ + (kt) + swc*8; \
    unsigned short* _l = As_ + ((bb)*2 + (h))*8192 + sr*64 + sc*8; \
    gload_lds16(_g0, _l); \
    gload_lds16(_g1, _l + 4096); \
} while (0)

#define STAGE_B(bb, h, kt) do { \
    const unsigned short* _g0 = Bm + (size_t)(n0 + (sr>>5)*64 + (h)*32 + (sr&31)) * IN_ + (kt) + swc*8; \
    const unsigned short* _g1 = Bm + (size_t)(n0 + 128 + (sr>>5)*64 + (h)*32 + (sr&31)) * IN_ + (kt) + swc*8; \
    unsigned short* _l = Bs_ + ((bb)*2 + (h))*8192 + sr*64 + sc*8; \
    gload_lds16(_g0, _l); \
    gload_lds16(_g1, _l + 4096); \
} while (0)

// A quadrant qm: row-tiles {2qm, 2qm+1}; 8 x ds_read_b128 into a_[2][4].
#define READ_A2(bb, qm) do { \
    const unsigned short* _Ab = As_ + ((bb)*2 + (qm))*8192; \
    _Pragma("unroll") \
    for (int ii = 0; ii < 2; ++ii) { \
        int _base = (alr0 + ii*32) * 64; \
        _Pragma("unroll") \
        for (int kk = 0; kk < 4; ++kk) \
            a_[ii][kk] = *reinterpret_cast<const bf16x8*>( \
                _Ab + _base + (((kk*2 + khi) ^ asw) * 8)); \
    } \
} while (0)

// B col-tile qn: 4 x ds_read_b128 into DST[4].
#define READ_B32(bb, qn, DST) do { \
    const unsigned short* _Bb = Bs_ + ((bb)*2 + (qn))*8192; \
    _Pragma("unroll") \
    for (int kk = 0; kk < 4; ++kk) \
        DST[kk] = *reinterpret_cast<const bf16x8*>( \
            _Bb + blr*64 + (((kk*2 + khi) ^ bsw) * 8)); \
} while (0)

// Quadrant burst: 2 row-tiles x 4 k-subtiles = 8 x mfma_32x32x16.
#define MFMA8(qm, qn, BS) \
    _Pragma("unroll") \
    for (int ii = 0; ii < 2; ++ii) { \
        _Pragma("unroll") \
        for (int kk = 0; kk < 4; ++kk) \
            acc32[(qm)*2+ii][qn] = __builtin_amdgcn_mfma_f32_32x32x16_bf16( \
                a_[ii][kk], BS[kk], acc32[(qm)*2+ii][qn], 0, 0, 0); \
    }

#define LGKM0 do { \
    asm volatile("s_waitcnt lgkmcnt(0)" ::: "memory"); \
    __builtin_amdgcn_sched_barrier(0); \
} while (0)

#define VMW asm volatile("s_waitcnt vmcnt(4)" ::: "memory")

// Superphase EVEN: quadrants (0,0) then (0,1) of buffer bb.
#define SP_EVEN(bb, S1, S2, VM_STMT) do { \
    READ_B32(bb, 0, bq0_); \
    READ_A2(bb, 0); \
    S1; S2; \
    LGKM0; \
    __builtin_amdgcn_s_setprio(1); \
    MFMA8(0, 0, bq0_) \
    __builtin_amdgcn_s_setprio(0); \
    READ_B32(bb, 1, bq1_); \
    LGKM0; \
    __builtin_amdgcn_s_setprio(1); \
    MFMA8(0, 1, bq1_) \
    __builtin_amdgcn_s_setprio(0); \
    VM_STMT; \
    __builtin_amdgcn_s_barrier(); \
} while (0)

// Superphase ODD: quadrants (1,1)+(1,0); bq0_/bq1_ carried from SP_EVEN.
#define SP_ODD(bb, S1, S2, VM_STMT) do { \
    READ_A2(bb, 1); \
    S1; S2; \
    LGKM0; \
    __builtin_amdgcn_s_setprio(1); \
    MFMA8(1, 1, bq1_) \
    MFMA8(1, 0, bq0_) \
    __builtin_amdgcn_s_setprio(0); \
    VM_STMT; \
    __builtin_amdgcn_s_barrier(); \
} while (0)

    f32x16 acc32[4][2] = {};
    bf16x8 a_[2][4], bq0_[4], bq1_[4];

    // Prologue (identical to r12): buf0 full (8 loads), buf1.A0 + buf1.B1 (4).
    STAGE_A(0, 0, 0);  STAGE_A(0, 1, 0);
    STAGE_B(0, 0, 0);  STAGE_B(0, 1, 0);
    STAGE_A(1, 0, 64); STAGE_B(1, 1, 64);
    asm volatile("s_waitcnt vmcnt(4)" ::: "memory");   // buf0 fully landed
    __builtin_amdgcn_s_barrier();

    // Main loop: iter it computes K-tiles 2it (buf0, SP1-2) and 2it+1 (buf1, SP3-4).
    // Stage ledger (== r7/r12):
    //  SP1: buf1.A1(2it+1), buf1.B0(2it+1)   SP2: buf0.A0(2it+2), buf0.B1(2it+2)
    //  SP3: buf0.A1(2it+2), buf0.B0(2it+2)   SP4: buf1.A0(2it+3), buf1.B1(2it+3)
    for (int it = 0; it < IN_ / 128; ++it) {
        int k1 = it * 128 + 64;
        int k2 = (it * 128 + 128) & (IN_ - 1);   // wrap: last-iter stages are dead
        int k3 = (it * 128 + 192) & (IN_ - 1);
        SP_EVEN(0, STAGE_A(1, 1, k1), STAGE_B(1, 0, k1), );     // SP1
        SP_ODD (0, STAGE_A(0, 0, k2), STAGE_B(0, 1, k2), VMW);  // SP2
        SP_EVEN(1, STAGE_A(0, 1, k2), STAGE_B(0, 0, k2), );     // SP3
        SP_ODD (1, STAGE_A(1, 0, k3), STAGE_B(1, 1, k3), VMW);  // SP4
    }

    // Epilogue (32x32 C/D layout): col = lane&31, row = (reg&3)+8*(reg>>2)+4*khi.
    float bv2[2];
    #pragma unroll
    for (int qn = 0; qn < 2; ++qn) bv2[qn] = bias[n0 + wn * 64 + qn * 32 + lane31];
    int crow0 = m0 + wm * 128 + 4 * khi;
    int ccol0 = n0 + wn * 64 + lane31;
    #pragma unroll
    for (int it2 = 0; it2 < 4; ++it2) {
        #pragma unroll
        for (int rq = 0; rq < 4; ++rq) {
            #pragma unroll
            for (int rr = 0; rr < 4; ++rr) {
                int row = crow0 + it2 * 32 + rq * 8 + rr;
                int reg = rq * 4 + rr;
                float* cp = C + (size_t)row * OUT_ + ccol0;
                cp[0]  = acc32[it2][0][reg] + bv2[0];
                cp[32] = acc32[it2][1][reg] + bv2[1];
            }
        }
    }
#undef STAGE_A
#undef STAGE_B
#undef READ_A2
#undef READ_B32
#undef MFMA8
#undef LGKM0
#undef VMW
#undef SP_EVEN
#undef SP_ODD
}

// ---------------------------------------------------------------------------
// Fallback (only if workspace too small): naive fp32, correct but slow.
__global__ __launch_bounds__(256) void naive_kernel(
        const float* __restrict__ in1, const float* __restrict__ in2a,
        const float* __restrict__ in2b, const float* __restrict__ W,
        const float* __restrict__ bias, float* __restrict__ out) {
    size_t id = (size_t)blockIdx.x * 256 + threadIdx.x;
    int s = (int)(id & (S_ - 1));
    size_t bo = id >> 11;
    int o = (int)(bo & (OUT_ - 1));
    int b = (int)(bo >> 11);
    const float* w = W + (size_t)o * IN_;
    float acc = bias[o];
    const float* x1 = in1 + (size_t)b * D1_ * S_ + s;
    for (int f = 0; f < D1_; ++f) acc += x1[(size_t)f * S_] * w[f];
    const float* x2 = in2a + (size_t)b * DJ_ * S_ + s;
    for (int f = 0; f < DJ_; ++f) acc += x2[(size_t)f * S_] * w[D1_ + f];
    const float* x3 = in2b + (size_t)b * DJ_ * S_ + s;
    for (int f = 0; f < DJ_; ++f) acc += x3[(size_t)f * S_] * w[D1_ + DJ_ + f];
    out[((size_t)b * S_ + s) * OUT_ + o] = acc;
}

// ---------------------------------------------------------------------------
extern "C" void kernel_launch(void* const* d_in, const int* in_sizes, int n_in,
                              void* d_out, int out_size, void* d_ws, size_t ws_size,
                              hipStream_t stream) {
    const float* in1  = (const float*)d_in[0];
    const float* in2a = (const float*)d_in[1];
    const float* in2b = (const float*)d_in[2];
    const float* W    = (const float*)d_in[3];
    const float* bias = (const float*)d_in[4];
    float* out = (float*)d_out;

    const size_t xt_bytes = (size_t)M_TOT * IN_ * 2;   // 67,108,864
    const size_t wb_bytes = (size_t)OUT_ * IN_ * 2;    //  8,388,608

    if (ws_size < xt_bytes + wb_bytes) {
        naive_kernel<<<(B_ * (size_t)OUT_ * S_) / 256, 256, 0, stream>>>(
            in1, in2a, in2b, W, bias, out);
        return;
    }

    unsigned short* Xt = (unsigned short*)d_ws;
    unsigned short* Wb = (unsigned short*)((char*)d_ws + xt_bytes);

    prep_kernel<<<8192 + (OUT_ * IN_) / (256 * 8), 256, 0, stream>>>(
        in1, in2a, in2b, W, Xt, Wb);
    gemm256_kernel<<<(M_TOT / 256) * (OUT_ / 256), 512, 0, stream>>>(Xt, Wb, bias, out);
}

// Round 14
// 159.690 us; speedup vs baseline: 1.1013x; 1.1013x over previous
//
#include <hip/hip_runtime.h>
#include <hip/hip_bf16.h>

// Problem constants
#define B_   8
#define D1_  1024
#define DJ_  512
#define S_   2048
#define OUT_ 2048
#define IN_  2048          // D1 + 2*DJ
#define M_TOT (B_ * S_)    // 16384

typedef __attribute__((ext_vector_type(8))) short          bf16x8;
typedef __attribute__((ext_vector_type(8))) unsigned short ushort8;
typedef __attribute__((ext_vector_type(4))) float          f32x4;

typedef __attribute__((address_space(3))) unsigned int as3_uint;
typedef __attribute__((address_space(1))) unsigned int as1_uint;

__device__ __forceinline__ unsigned short f2bf(float f) {
    union { float f; unsigned u; } v; v.f = f;
    unsigned r = v.u + 0x7FFF + ((v.u >> 16) & 1);   // round-to-nearest-even
    return (unsigned short)(r >> 16);
}

__device__ __forceinline__ void gload_lds16(const void* g, const void* l) {
    __builtin_amdgcn_global_load_lds(
        (const as1_uint*)(unsigned long long)g,
        (as3_uint*)(unsigned int)(unsigned long long)l,
        16, 0, 0);
}

// ---------------------------------------------------------------------------
// Kernel 1 (merged prep): blocks [0,8192) = concat+transpose+cvt of X;
// blocks [8192,10240) = W f32->bf16.  Runs at ~memory roofline (~33us).
__global__ __launch_bounds__(256) void prep_kernel(
        const float* __restrict__ in1, const float* __restrict__ in2a,
        const float* __restrict__ in2b, const float* __restrict__ W,
        unsigned short* __restrict__ Xt, unsigned short* __restrict__ Wb) {
    int bid = blockIdx.x;
    if (bid >= 8192) {
        size_t i = (size_t)(bid - 8192) * 256 + threadIdx.x;
        const float4* p = reinterpret_cast<const float4*>(W) + i * 2;
        float4 a = p[0], c = p[1];
        ushort8 h;
        h[0] = f2bf(a.x); h[1] = f2bf(a.y); h[2] = f2bf(a.z); h[3] = f2bf(a.w);
        h[4] = f2bf(c.x); h[5] = f2bf(c.y); h[6] = f2bf(c.z); h[7] = f2bf(c.w);
        *(reinterpret_cast<ushort8*>(Wb) + i) = h;
        return;
    }
    __shared__ float tile[64][65];
    int st = bid & 31;
    int ft = (bid >> 5) & 31;
    int b  = bid >> 10;
    int f0 = ft << 6, s0 = st << 6;

    const float* src; int frel;
    if (f0 < D1_)             { src = in1  + (size_t)b * D1_ * S_; frel = f0; }
    else if (f0 < D1_ + DJ_)  { src = in2a + (size_t)b * DJ_ * S_; frel = f0 - D1_; }
    else                      { src = in2b + (size_t)b * DJ_ * S_; frel = f0 - (D1_ + DJ_); }

    int t = threadIdx.x;
    int tr = t >> 4, tc = t & 15;
    #pragma unroll
    for (int i = 0; i < 4; ++i) {
        int fi = tr + i * 16;
        const float4 v = *reinterpret_cast<const float4*>(
            &src[(size_t)(frel + fi) * S_ + s0 + tc * 4]);
        tile[fi][tc * 4 + 0] = v.x; tile[fi][tc * 4 + 1] = v.y;
        tile[fi][tc * 4 + 2] = v.z; tile[fi][tc * 4 + 3] = v.w;
    }
    __syncthreads();
    int si0 = t >> 3, fx = t & 7;
    #pragma unroll
    for (int i = 0; i < 2; ++i) {
        int si = si0 + i * 32;
        ushort8 h;
        #pragma unroll
        for (int j = 0; j < 8; ++j) h[j] = f2bf(tile[fx * 8 + j][si]);
        *reinterpret_cast<ushort8*>(
            &Xt[(size_t)(b * S_ + s0 + si) * IN_ + f0 + fx * 8]) = h;
    }
}

// ---------------------------------------------------------------------------
// Kernel 2: 256x256 bf16 GEMM (= round-12 optimum: r7 skeleton + B double-set).
// C[M,N] = A[M,K]*B[N,K]^T + bias.  512 thr = 8 waves (2M x 4N).
// LDS: As_/Bs_ [2 buf][2 region][128][64] bf16 = 128 KiB.  T2 swizzle both.
// 16x16x32 MFMA (conflict-free with this staging; 32x32 is structurally
// 4-way-bank-conflicted here -- r13 post-mortem).  b0_/b1_ persist across the
// SP pair; per-wave LDS reads at the 24 KB/K-tile floor.

__global__ __launch_bounds__(512, 2) void gemm256_kernel(
        const unsigned short* __restrict__ A,    // Xt [M_TOT][IN_] bf16
        const unsigned short* __restrict__ Bm,   // Wb [OUT_][IN_] bf16
        const float* __restrict__ bias,
        float* __restrict__ C) {
    __shared__ unsigned short As_[32768];   // [2][2][128][64]
    __shared__ unsigned short Bs_[32768];

    int bid = blockIdx.x;
    // XCD swizzle: nwg = 512 = 8 * 64 (divisible -> simple form bijective)
    int swz = (bid & 7) * 64 + (bid >> 3);
    int m0 = (swz >> 3) * 256;
    int n0 = (swz & 7) * 256;

    int t = threadIdx.x;
    int lane = t & 63, wave = t >> 6;
    int wm = wave >> 2;
    int wn = wave & 3;
    int fr = lane & 15;
    int fkslot = lane >> 4;

    // staging constants
    int sr  = t >> 3;
    int sc  = t & 7;
    int swc = sc ^ (sr & 7);       // pre-swizzled global k-slot (involution)

    // ds_read swizzled slot offsets (elements) for kk=0,1
    int sl0 = ((fkslot)     ^ (fr & 7)) * 8;
    int sl1 = ((4 + fkslot) ^ (fr & 7)) * 8;
    int arow = wm * 64 + fr;
    int brow = wn * 32 + fr;

#define STAGE_A(bb, h, kt) do { \
    const unsigned short* _g0 = A + (size_t)(m0 + (h)*64 + sr) * IN_ + (kt) + swc*8; \
    const unsigned short* _g1 = A + (size_t)(m0 + 128 + (h)*64 + sr) * IN_ + (kt) + swc*8; \
    unsigned short* _l = As_ + ((bb)*2 + (h))*8192 + sr*64 + sc*8; \
    gload_lds16(_g0, _l); \
    gload_lds16(_g1, _l + 4096); \
} while (0)

#define STAGE_B(bb, h, kt) do { \
    const unsigned short* _g0 = Bm + (size_t)(n0 + (sr>>5)*64 + (h)*32 + (sr&31)) * IN_ + (kt) + swc*8; \
    const unsigned short* _g1 = Bm + (size_t)(n0 + 128 + (sr>>5)*64 + (h)*32 + (sr&31)) * IN_ + (kt) + swc*8; \
    unsigned short* _l = Bs_ + ((bb)*2 + (h))*8192 + sr*64 + sc*8; \
    gload_lds16(_g0, _l); \
    gload_lds16(_g1, _l + 4096); \
} while (0)

#define READ_A(bb, qm) do { \
    const unsigned short* _Ab = As_ + ((bb)*2 + (qm))*8192; \
    _Pragma("unroll") \
    for (int i = 0; i < 4; ++i) { \
        int rr = (arow + i*16) * 64; \
        a_[i][0] = *reinterpret_cast<const bf16x8*>(_Ab + rr + sl0); \
        a_[i][1] = *reinterpret_cast<const bf16x8*>(_Ab + rr + sl1); \
    } \
} while (0)

#define READ_B(bb, qn, DST) do { \
    const unsigned short* _Bb = Bs_ + ((bb)*2 + (qn))*8192; \
    _Pragma("unroll") \
    for (int j = 0; j < 2; ++j) { \
        int rr = (brow + j*16) * 64; \
        DST[j][0] = *reinterpret_cast<const bf16x8*>(_Bb + rr + sl0); \
        DST[j][1] = *reinterpret_cast<const bf16x8*>(_Bb + rr + sl1); \
    } \
} while (0)

#define MFMA4(qm, qn, BS) \
    _Pragma("unroll") \
    for (int i = 0; i < 4; ++i) { \
        _Pragma("unroll") \
        for (int j = 0; j < 2; ++j) { \
            acc[(qm)*4+i][(qn)*2+j] = __builtin_amdgcn_mfma_f32_16x16x32_bf16( \
                a_[i][0], BS[j][0], acc[(qm)*4+i][(qn)*2+j], 0, 0, 0); \
            acc[(qm)*4+i][(qn)*2+j] = __builtin_amdgcn_mfma_f32_16x16x32_bf16( \
                a_[i][1], BS[j][1], acc[(qm)*4+i][(qn)*2+j], 0, 0, 0); \
        } \
    }

#define LGKM0 do { \
    asm volatile("s_waitcnt lgkmcnt(0)" ::: "memory"); \
    __builtin_amdgcn_sched_barrier(0); \
} while (0)

#define VMW asm volatile("s_waitcnt vmcnt(4)" ::: "memory")

// Superphase EVEN: quadrants (0,0) then (0,1) of buffer bb.
#define SP_EVEN(bb, S1, S2, VM_STMT) do { \
    READ_B(bb, 0, b0_); \
    READ_A(bb, 0); \
    S1; S2; \
    LGKM0; \
    __builtin_amdgcn_s_setprio(1); \
    MFMA4(0, 0, b0_) \
    __builtin_amdgcn_s_setprio(0); \
    READ_B(bb, 1, b1_); \
    LGKM0; \
    __builtin_amdgcn_s_setprio(1); \
    MFMA4(0, 1, b1_) \
    __builtin_amdgcn_s_setprio(0); \
    VM_STMT; \
    __builtin_amdgcn_s_barrier(); \
} while (0)

// Superphase ODD: quadrants (1,1)+(1,0); b0_/b1_ carried in from SP_EVEN.
#define SP_ODD(bb, S1, S2, VM_STMT) do { \
    READ_A(bb, 1); \
    S1; S2; \
    LGKM0; \
    __builtin_amdgcn_s_setprio(1); \
    MFMA4(1, 1, b1_) \
    MFMA4(1, 0, b0_) \
    __builtin_amdgcn_s_setprio(0); \
    VM_STMT; \
    __builtin_amdgcn_s_barrier(); \
} while (0)

    f32x4 acc[8][4] = {};
    bf16x8 a_[4][2], b0_[2][2], b1_[2][2];

    // Prologue: buf0 full (8 loads), buf1.A0 + buf1.B1 (4).
    STAGE_A(0, 0, 0);  STAGE_A(0, 1, 0);
    STAGE_B(0, 0, 0);  STAGE_B(0, 1, 0);
    STAGE_A(1, 0, 64); STAGE_B(1, 1, 64);
    asm volatile("s_waitcnt vmcnt(4)" ::: "memory");   // buf0 fully landed
    __builtin_amdgcn_s_barrier();

    // Main loop: iter it computes K-tiles 2it (buf0, SP1-2) and 2it+1 (buf1, SP3-4).
    // Stage ledger:
    //  SP1: buf1.A1(2it+1), buf1.B0(2it+1)   SP2: buf0.A0(2it+2), buf0.B1(2it+2)
    //  SP3: buf0.A1(2it+2), buf0.B0(2it+2)   SP4: buf1.A0(2it+3), buf1.B1(2it+3)
    for (int it = 0; it < IN_ / 128; ++it) {
        int k1 = it * 128 + 64;
        int k2 = (it * 128 + 128) & (IN_ - 1);   // wrap: last-iter stages are dead
        int k3 = (it * 128 + 192) & (IN_ - 1);
        SP_EVEN(0, STAGE_A(1, 1, k1), STAGE_B(1, 0, k1), );     // SP1
        SP_ODD (0, STAGE_A(0, 0, k2), STAGE_B(0, 1, k2), VMW);  // SP2
        SP_EVEN(1, STAGE_A(0, 1, k2), STAGE_B(0, 0, k2), );     // SP3
        SP_ODD (1, STAGE_A(1, 0, k3), STAGE_B(1, 1, k3), VMW);  // SP4
    }

    // Epilogue: bias + store. C/D layout: col = lane&15, row = (lane>>4)*4 + reg.
    float bv[4];
    #pragma unroll
    for (int n_ = 0; n_ < 4; ++n_) bv[n_] = bias[n0 + wn * 64 + n_ * 16 + fr];
    int crow0 = m0 + wm * 128 + (lane >> 4) * 4;
    int ccol0 = n0 + wn * 64 + fr;
    #pragma unroll
    for (int mi = 0; mi < 8; ++mi) {
        #pragma unroll
        for (int r_ = 0; r_ < 4; ++r_) {
            float* cp = C + (size_t)(crow0 + mi * 16 + r_) * OUT_ + ccol0;
            #pragma unroll
            for (int n_ = 0; n_ < 4; ++n_) cp[n_ * 16] = acc[mi][n_][r_] + bv[n_];
        }
    }
#undef STAGE_A
#undef STAGE_B
#undef READ_A
#undef READ_B
#undef MFMA4
#undef LGKM0
#undef VMW
#undef SP_EVEN
#undef SP_ODD
}

// ---------------------------------------------------------------------------
// Fallback (only if workspace too small): naive fp32, correct but slow.
__global__ __launch_bounds__(256) void naive_kernel(
        const float* __restrict__ in1, const float* __restrict__ in2a,
        const float* __restrict__ in2b, const float* __restrict__ W,
        const float* __restrict__ bias, float* __restrict__ out) {
    size_t id = (size_t)blockIdx.x * 256 + threadIdx.x;
    int s = (int)(id & (S_ - 1));
    size_t bo = id >> 11;
    int o = (int)(bo & (OUT_ - 1));
    int b = (int)(bo >> 11);
    const float* w = W + (size_t)o * IN_;
    float acc = bias[o];
    const float* x1 = in1 + (size_t)b * D1_ * S_ + s;
    for (int f = 0; f < D1_; ++f) acc += x1[(size_t)f * S_] * w[f];
    const float* x2 = in2a + (size_t)b * DJ_ * S_ + s;
    for (int f = 0; f < DJ_; ++f) acc += x2[(size_t)f * S_] * w[D1_ + f];
    const float* x3 = in2b + (size_t)b * DJ_ * S_ + s;
    for (int f = 0; f < DJ_; ++f) acc += x3[(size_t)f * S_] * w[D1_ + DJ_ + f];
    out[((size_t)b * S_ + s) * OUT_ + o] = acc;
}

// ---------------------------------------------------------------------------
extern "C" void kernel_launch(void* const* d_in, const int* in_sizes, int n_in,
                              void* d_out, int out_size, void* d_ws, size_t ws_size,
                              hipStream_t stream) {
    const float* in1  = (const float*)d_in[0];
    const float* in2a = (const float*)d_in[1];
    const float* in2b = (const float*)d_in[2];
    const float* W    = (const float*)d_in[3];
    const float* bias = (const float*)d_in[4];
    float* out = (float*)d_out;

    const size_t xt_bytes = (size_t)M_TOT * IN_ * 2;   // 67,108,864
    const size_t wb_bytes = (size_t)OUT_ * IN_ * 2;    //  8,388,608

    if (ws_size < xt_bytes + wb_bytes) {
        naive_kernel<<<(B_ * (size_t)OUT_ * S_) / 256, 256, 0, stream>>>(
            in1, in2a, in2b, W, bias, out);
        return;
    }

    unsigned short* Xt = (unsigned short*)d_ws;
    unsigned short* Wb = (unsigned short*)((char*)d_ws + xt_bytes);

    prep_kernel<<<8192 + (OUT_ * IN_) / (256 * 8), 256, 0, stream>>>(
        in1, in2a, in2b, W, Xt, Wb);
    gemm256_kernel<<<(M_TOT / 256) * (OUT_ / 256), 512, 0, stream>>>(Xt, Wb, bias, out);
}